// Round 3
// baseline (658.662 us; speedup 1.0000x reference)
//
#include <hip/hip_runtime.h>
#include <hip/hip_bf16.h>
#include <math.h>

typedef unsigned short u16;
typedef unsigned int u32;
typedef __attribute__((ext_vector_type(8))) short short8;
typedef __attribute__((ext_vector_type(4))) float floatx4;

__device__ __forceinline__ float bf2f(u16 u) { return __uint_as_float(((u32)u) << 16); }
__device__ __forceinline__ u16 f2bf(float f) {
  u32 u = __float_as_uint(f);
  u32 r = u + 0x7fffu + ((u >> 16) & 1u);
  return (u16)(r >> 16);
}

// workspace layout (bytes):
//   [0, 393216)          float wsb[4 cat][6 h][256 tid][16]    bias+mask frags
//   [393216, 614400)     u16   wsq[36 T][6 s][64 lane][8]      qkv weights, frag order
//   [614400, 688128)     u16   wsp[6 h][12 nt][64 lane][8]     proj weights, frag order
//   [688128, 983040)     u16   wsm1[24 ch][2 n][6 s][64][8]    mlp w1, frag order
//   [983040, 1277952)    u16   wsm2[24 ch][12 ct][64][8]       mlp w2, frag order
#define WSB_OFF  0
#define WSQ_OFF  393216
#define WSP_OFF  614400
#define WSM1_OFF 688128
#define WSM2_OFF 983040

// ---------------------------------------------------------------------------
// k_prep: one-time weight/bias repack into d_ws (idempotent, ~10us).
// ---------------------------------------------------------------------------
__global__ __launch_bounds__(256) void k_prep(
    const float* __restrict__ qkvw, const float* __restrict__ projw,
    const float* __restrict__ rpb,
    const float* __restrict__ w1, const float* __restrict__ w2,
    float* __restrict__ wsb, u16* __restrict__ wsq, u16* __restrict__ wsp,
    u16* __restrict__ wsm1, u16* __restrict__ wsm2)
{
  const int tid0 = blockIdx.x * 256 + threadIdx.x;
  const int NT = gridDim.x * 256;
  // qkv frags: T = mat*12 + h*2 + ct ; row = mat*192 + (h*2+ct)*16 + (lane&15)
  for (int idx = tid0; idx < 110592; idx += NT) {
    int e = idx & 7, lane = (idx >> 3) & 63, rest = idx >> 9;
    int s = rest % 6, T = rest / 6;
    int mat = T / 12, hct = T % 12;
    int row = mat * 192 + hct * 16 + (lane & 15);
    int col = 32 * s + 8 * (lane >> 4) + e;
    float v = qkvw[(size_t)row * 192 + col];
    if (mat == 0) v *= 0.1767766952966369f;   // fold q scale into Wq
    wsq[idx] = f2bf(v);
  }
  // proj frags: row = 16*nt + (lane&15) ; col = 32*h + 8*(lane>>4)+e
  for (int idx = tid0; idx < 36864; idx += NT) {
    int e = idx & 7, lane = (idx >> 3) & 63, rest = idx >> 9;
    int nt = rest % 12, h = rest / 12;
    int row = 16 * nt + (lane & 15);
    int col = 32 * h + 8 * (lane >> 4) + e;
    wsp[idx] = f2bf(projw[(size_t)row * 192 + col]);
  }
  // mlp w1 frags: rest = (ch*2+n)*6 + s ; row = ch*32 + n*16 + (lane&15)
  for (int idx = tid0; idx < 147456; idx += NT) {
    int e = idx & 7, lane = (idx >> 3) & 63, rest = idx >> 9;
    int s = rest % 6, t = rest / 6;
    int n = t & 1, ch = t >> 1;
    wsm1[idx] = f2bf(w1[(size_t)(ch * 32 + n * 16 + (lane & 15)) * 192
                        + 32 * s + 8 * (lane >> 4) + e]);
  }
  // mlp w2 frags: rest = ch*12 + ct ; row = ct*16 + (lane&15), col = ch*32+8q+e
  for (int idx = tid0; idx < 147456; idx += NT) {
    int e = idx & 7, lane = (idx >> 3) & 63, rest = idx >> 9;
    int ct = rest % 12, ch = rest / 12;
    wsm2[idx] = f2bf(w2[(size_t)(ct * 16 + (lane & 15)) * 768
                        + ch * 32 + 8 * (lane >> 4) + e]);
  }
  // bias+mask: idx = ((cat*6+h)*256 + tid)*16 + nt*4 + r
  for (int idx = tid0; idx < 98304; idx += NT) {
    int f16 = idx & 15; int nt = f16 >> 2, r = f16 & 3;
    int t = (idx >> 4) & 255; int rest = idx >> 12;
    int h = rest % 6, cat = rest / 6;
    int w = t >> 6, m = t & 15, ql = (t >> 4) & 3;
    int i = 16 * w + 4 * ql + r, j = 16 * nt + m;
    int ir = i >> 3, ic = i & 7, jr = j >> 3, jc = j & 7;
    float v = rpb[((ir - jr + 7) * 15 + (ic - jc + 7)) * 6 + h];
    int catH = cat >> 1, catW = cat & 1;
    int ci = (catH ? ((ir < 4) ? 1 : 2) : 0) * 3 + (catW ? ((ic < 4) ? 1 : 2) : 0);
    int cj = (catH ? ((jr < 4) ? 1 : 2) : 0) * 3 + (catW ? ((jc < 4) ? 1 : 2) : 0);
    if (ci != cj) v -= 100.f;
    wsb[idx] = v;
  }
}

// ---------------------------------------------------------------------------
// k_attn: LN1 + shifted-window attention + proj + residual. (unchanged)
// 2048 blocks x 256 threads (4 waves). 2 barriers per head.
// ---------------------------------------------------------------------------
__global__ __launch_bounds__(256) void k_attn(
    const float* __restrict__ x,
    const float* __restrict__ g1, const float* __restrict__ b1,
    const float* __restrict__ projb,
    const float* __restrict__ wsb, const u16* __restrict__ wsq,
    const u16* __restrict__ wsp,
    float* __restrict__ out)
{
  __shared__ __align__(16) u16 xn[64][200];   // LN1 out [token][ch]   25600 B
  __shared__ __align__(16) u16 qs[64][40];    // q (scaled)            5120 B
  __shared__ __align__(16) u16 ks[64][40];    // k                     5120 B
  __shared__ __align__(16) u16 vT[32][72];    // v^T [ch][token]       4608 B
  __shared__ __align__(16) u16 PO[4608];      // wave-private P/Oh     9216 B

  const int tid = threadIdx.x;
  const int blk = blockIdx.x;
  const int b  = blk >> 10;
  const int wh = (blk >> 5) & 31;
  const int ww = blk & 31;

  // ---- LN1 + gather (roll -4 folded into index); token-major bf16 ----
  {
    const int t = tid >> 2, l4 = tid & 3;
    const int rr = t >> 3, cc = t & 7;
    const int oh = (wh * 8 + rr + 4) & 255;
    const int ow = (ww * 8 + cc + 4) & 255;
    const float* px = x + (((size_t)b * 65536 + (size_t)oh * 256 + ow) * 192) + l4 * 48;
    float rv[48];
    float s = 0.f, ss = 0.f;
    const float4* p4 = (const float4*)px;
    #pragma unroll
    for (int i = 0; i < 12; ++i) {
      float4 v = p4[i];
      rv[i*4+0] = v.x; rv[i*4+1] = v.y; rv[i*4+2] = v.z; rv[i*4+3] = v.w;
      s  += v.x + v.y + v.z + v.w;
      ss += v.x*v.x + v.y*v.y + v.z*v.z + v.w*v.w;
    }
    s += __shfl_xor(s, 1);  s += __shfl_xor(s, 2);
    ss += __shfl_xor(ss, 1); ss += __shfl_xor(ss, 2);
    const float mean = s * (1.f / 192.f);
    const float var  = ss * (1.f / 192.f) - mean * mean;
    const float rstd = rsqrtf(var + 1e-5f);
    const int c0 = l4 * 48;
    #pragma unroll
    for (int i = 0; i < 12; ++i) {
      ushort4 o;
      o.x = f2bf((rv[i*4+0] - mean) * rstd * g1[c0+i*4+0] + b1[c0+i*4+0]);
      o.y = f2bf((rv[i*4+1] - mean) * rstd * g1[c0+i*4+1] + b1[c0+i*4+1]);
      o.z = f2bf((rv[i*4+2] - mean) * rstd * g1[c0+i*4+2] + b1[c0+i*4+2]);
      o.w = f2bf((rv[i*4+3] - mean) * rstd * g1[c0+i*4+3] + b1[c0+i*4+3]);
      *(ushort4*)&xn[t][c0 + i*4] = o;
    }
  }

  const int w    = tid >> 6;         // wave id
  const int lane = tid & 63;
  const int m    = tid & 15;
  const int ql   = (tid >> 4) & 3;
  const int ct   = w >> 1;           // channel tile (0: ch 0-15, 1: ch 16-31)
  const int tb   = (w & 1) * 2;      // token-tile base (0 or 2)
  const int cat  = ((wh == 31) ? 2 : 0) | ((ww == 31) ? 1 : 0);
  const float* pbias = wsb + ((size_t)(cat * 6) * 256 + tid) * 16;
  const int po = w * 1152;           // this wave's private PO region (u16 idx)

  floatx4 acc[12];
  #pragma unroll
  for (int nt = 0; nt < 12; ++nt) acc[nt] = (floatx4){0.f, 0.f, 0.f, 0.f};

  __syncthreads();

  #pragma unroll 1
  for (int h = 0; h < 6; ++h) {
    // ---- QKV: wave computes (q,k,v) x (2 token-tiles) for its ch-tile ----
    {
      const u16* wqp = wsq + (size_t)(h * 2 + ct) * 3072 + lane * 8;
      floatx4 dq[2], dk[2], dv[2];
      #pragma unroll
      for (int t = 0; t < 2; ++t) {
        dq[t] = (floatx4){0.f,0.f,0.f,0.f};
        dk[t] = (floatx4){0.f,0.f,0.f,0.f};
        dv[t] = (floatx4){0.f,0.f,0.f,0.f};
      }
      #pragma unroll
      for (int s = 0; s < 6; ++s) {
        short8 a0 = *(const short8*)&xn[16*tb + m][32*s + 8*ql];
        short8 a1 = *(const short8*)&xn[16*tb + 16 + m][32*s + 8*ql];
        short8 bq = *(const short8*)(wqp + s*512);
        short8 bk = *(const short8*)(wqp + 36864 + s*512);
        short8 bv = *(const short8*)(wqp + 73728 + s*512);
        dq[0] = __builtin_amdgcn_mfma_f32_16x16x32_bf16(a0, bq, dq[0], 0, 0, 0);
        dq[1] = __builtin_amdgcn_mfma_f32_16x16x32_bf16(a1, bq, dq[1], 0, 0, 0);
        dk[0] = __builtin_amdgcn_mfma_f32_16x16x32_bf16(a0, bk, dk[0], 0, 0, 0);
        dk[1] = __builtin_amdgcn_mfma_f32_16x16x32_bf16(a1, bk, dk[1], 0, 0, 0);
        dv[0] = __builtin_amdgcn_mfma_f32_16x16x32_bf16(a0, bv, dv[0], 0, 0, 0);
        dv[1] = __builtin_amdgcn_mfma_f32_16x16x32_bf16(a1, bv, dv[1], 0, 0, 0);
      }
      #pragma unroll
      for (int t = 0; t < 2; ++t) {
        #pragma unroll
        for (int r = 0; r < 4; ++r) {
          qs[16*(tb+t) + 4*ql + r][ct*16 + m] = f2bf(dq[t][r]);
          ks[16*(tb+t) + 4*ql + r][ct*16 + m] = f2bf(dk[t][r]);
        }
        ushort4 o;
        o.x = f2bf(dv[t][0]); o.y = f2bf(dv[t][1]);
        o.z = f2bf(dv[t][2]); o.w = f2bf(dv[t][3]);
        *(ushort4*)&vT[ct*16 + m][16*(tb+t) + 4*ql] = o;
      }
    }
    __syncthreads();                 // bar1: q/k/vT ready

    // ---- S = q.k^T + (bias+mask as C-operand); softmax in-register ----
    floatx4 sf[4];
    {
      short8 aq = *(const short8*)&qs[16*w + m][8*ql];
      const float* pb = pbias + (size_t)h * 4096;
      #pragma unroll
      for (int nt = 0; nt < 4; ++nt) {
        float4 b4 = *(const float4*)(pb + nt*4);
        short8 bk = *(const short8*)&ks[16*nt + m][8*ql];
        sf[nt] = __builtin_amdgcn_mfma_f32_16x16x32_bf16(
            aq, bk, (floatx4){b4.x, b4.y, b4.z, b4.w}, 0, 0, 0);
      }
    }
    {
      float mxr[4] = {-3.0e38f, -3.0e38f, -3.0e38f, -3.0e38f};
      #pragma unroll
      for (int nt = 0; nt < 4; ++nt)
        #pragma unroll
        for (int r = 0; r < 4; ++r) mxr[r] = fmaxf(mxr[r], sf[nt][r]);
      #pragma unroll
      for (int d = 1; d <= 8; d <<= 1)
        #pragma unroll
        for (int r = 0; r < 4; ++r) mxr[r] = fmaxf(mxr[r], __shfl_xor(mxr[r], d));
      float smr[4] = {0.f, 0.f, 0.f, 0.f};
      #pragma unroll
      for (int nt = 0; nt < 4; ++nt)
        #pragma unroll
        for (int r = 0; r < 4; ++r) {
          float e = __expf(sf[nt][r] - mxr[r]);
          sf[nt][r] = e;
          smr[r] += e;
        }
      #pragma unroll
      for (int d = 1; d <= 8; d <<= 1)
        #pragma unroll
        for (int r = 0; r < 4; ++r) smr[r] += __shfl_xor(smr[r], d);
      // write P (wave-private; in-order same-wave DS, no barrier)
      #pragma unroll
      for (int r = 0; r < 4; ++r) {
        const float inv = 1.f / smr[r];
        #pragma unroll
        for (int nt = 0; nt < 4; ++nt)
          PO[po + (4*ql + r)*72 + 16*nt + m] = f2bf(sf[nt][r] * inv);
      }
    }

    // ---- PV: O[tok][ch] = P[16 tok x 64] @ vT[32 ch x 64]^T ----
    floatx4 of[2];
    of[0] = (floatx4){0.f,0.f,0.f,0.f}; of[1] = (floatx4){0.f,0.f,0.f,0.f};
    #pragma unroll
    for (int s = 0; s < 2; ++s) {
      short8 ap = *(const short8*)&PO[po + m*72 + 32*s + 8*ql];
      #pragma unroll
      for (int mt = 0; mt < 2; ++mt) {
        short8 bv = *(const short8*)&vT[16*mt + m][32*s + 8*ql];
        of[mt] = __builtin_amdgcn_mfma_f32_16x16x32_bf16(ap, bv, of[mt], 0, 0, 0);
      }
    }
    __syncthreads();                 // bar2: shared q/k/vT reads done

    // ---- Oh (wave-private, overlays P) + proj accumulate ----
    #pragma unroll
    for (int mt = 0; mt < 2; ++mt)
      #pragma unroll
      for (int r = 0; r < 4; ++r)
        PO[po + (4*ql + r)*40 + 16*mt + m] = f2bf(of[mt][r]);
    {
      short8 ao = *(const short8*)&PO[po + m*40 + 8*ql];
      const u16* wpp = wsp + (size_t)h * 6144 + lane * 8;
      #pragma unroll
      for (int nt = 0; nt < 12; ++nt) {
        short8 bw = *(const short8*)(wpp + nt*512);
        acc[nt] = __builtin_amdgcn_mfma_f32_16x16x32_bf16(ao, bw, acc[nt], 0, 0, 0);
      }
    }
  }

  // ---- epilogue: out = x + proj + projb (window-reverse + roll via gather) ----
  {
    size_t rbase[4];
    #pragma unroll
    for (int r = 0; r < 4; ++r) {
      const int i  = 16*w + 4*ql + r;
      const int ir = i >> 3, ic = i & 7;
      const int oh = (wh * 8 + ir + 4) & 255;
      const int ow = (ww * 8 + ic + 4) & 255;
      rbase[r] = ((size_t)b * 65536 + (size_t)oh * 256 + ow) * 192;
    }
    #pragma unroll
    for (int nt = 0; nt < 12; ++nt) {
      const int c = 16*nt + m;
      const float pb = projb[c];
      #pragma unroll
      for (int r = 0; r < 4; ++r) {
        const size_t idx = rbase[r] + c;
        out[idx] = x[idx] + acc[nt][r] + pb;
      }
    }
  }
}

// ---------------------------------------------------------------------------
// k_mlp v2: LN2 + MLP(GELU) + residual, in-place on d_out.
// Weights read as pre-packed bf16 B-fragments directly from d_ws (L2-resident).
// No staging, no f2bf on weights, ONE barrier total. LDS 30720 B.
// ---------------------------------------------------------------------------
__global__ __launch_bounds__(256) void k_mlp(
    const float* __restrict__ g2, const float* __restrict__ b2,
    const u16* __restrict__ wsm1, const float* __restrict__ bm1,
    const u16* __restrict__ wsm2, const float* __restrict__ bm2,
    float* __restrict__ io)
{
  __shared__ u16 xn[64][200];      // LN2 out, bf16 [token][ch]      (25600 B)
  __shared__ u16 gs[4][16][40];    // gelu(H) wave-private transpose (5120 B)

  const int tid = threadIdx.x;
  const size_t tok0 = (size_t)blockIdx.x * 64;

  // ---- LN2 (4 threads / token) -> xn bf16 ----
  {
    const int t = tid >> 2, l4 = tid & 3;
    const float* px = io + (tok0 + t) * 192 + l4 * 48;
    float rv[48];
    float s = 0.f, ss = 0.f;
    const float4* p4 = (const float4*)px;
    #pragma unroll
    for (int i = 0; i < 12; ++i) {
      float4 v = p4[i];
      rv[i*4+0] = v.x; rv[i*4+1] = v.y; rv[i*4+2] = v.z; rv[i*4+3] = v.w;
      s += v.x + v.y + v.z + v.w;
      ss += v.x*v.x + v.y*v.y + v.z*v.z + v.w*v.w;
    }
    s += __shfl_xor(s, 1);  s += __shfl_xor(s, 2);
    ss += __shfl_xor(ss, 1); ss += __shfl_xor(ss, 2);
    const float mean = s * (1.f / 192.f);
    const float var  = ss * (1.f / 192.f) - mean * mean;
    const float rstd = rsqrtf(var + 1e-5f);
    const int c0 = l4 * 48;
    #pragma unroll
    for (int i = 0; i < 12; ++i) {
      ushort4 o;
      o.x = f2bf((rv[i*4+0] - mean) * rstd * g2[c0+i*4+0] + b2[c0+i*4+0]);
      o.y = f2bf((rv[i*4+1] - mean) * rstd * g2[c0+i*4+1] + b2[c0+i*4+1]);
      o.z = f2bf((rv[i*4+2] - mean) * rstd * g2[c0+i*4+2] + b2[c0+i*4+2]);
      o.w = f2bf((rv[i*4+3] - mean) * rstd * g2[c0+i*4+3] + b2[c0+i*4+3]);
      *(ushort4*)&xn[t][c0 + i*4] = o;
    }
  }
  __syncthreads();                 // xn ready (only barrier)

  const int w = tid >> 6;          // wave: owns tokens [16w,16w+16)
  const int lane = tid & 63;
  const int m = lane & 15;
  const int q = lane >> 4;

  // A-fragments are chunk-invariant: hoist once (24 VGPRs)
  short8 a_all[6];
  #pragma unroll
  for (int s = 0; s < 6; ++s)
    a_all[s] = *(const short8*)&xn[16 * w + m][32 * s + 8 * q];

  floatx4 c2acc[12];
  #pragma unroll
  for (int ct = 0; ct < 12; ++ct) c2acc[ct] = (floatx4){0.f, 0.f, 0.f, 0.f};

  const u16* pm1 = wsm1 + lane * 8;
  const u16* pm2 = wsm2 + lane * 8;

  #pragma unroll 1
  for (int ch = 0; ch < 24; ++ch) {
    // GEMM1: H tile 16x32, K=192; B-frags straight from global (L2)
    const u16* w1p = pm1 + (size_t)ch * 6144;
    floatx4 h0 = (floatx4){0.f, 0.f, 0.f, 0.f};
    floatx4 h1 = (floatx4){0.f, 0.f, 0.f, 0.f};
    #pragma unroll
    for (int s = 0; s < 6; ++s) {
      short8 b0 = *(const short8*)(w1p + s * 512);
      short8 b1 = *(const short8*)(w1p + 3072 + s * 512);
      h0 = __builtin_amdgcn_mfma_f32_16x16x32_bf16(a_all[s], b0, h0, 0, 0, 0);
      h1 = __builtin_amdgcn_mfma_f32_16x16x32_bf16(a_all[s], b1, h1, 0, 0, 0);
    }

    // bias + exact GELU, wave-private LDS transpose (no barrier needed)
    const int c0 = ch * 32;
    {
      const float bb0 = bm1[c0 + m];
      const float bb1 = bm1[c0 + 16 + m];
      #pragma unroll
      for (int r = 0; r < 4; ++r) {
        float v0 = h0[r] + bb0;
        float v1 = h1[r] + bb1;
        float g0 = 0.5f * v0 * (1.f + erff(v0 * 0.70710678118654752f));
        float g1 = 0.5f * v1 * (1.f + erff(v1 * 0.70710678118654752f));
        gs[w][q * 4 + r][m] = f2bf(g0);
        gs[w][q * 4 + r][16 + m] = f2bf(g1);
      }
    }

    // GEMM2: C2[16x192] += G[16x32] @ w2chunk, K=32; B-frags from global
    {
      short8 ap = *(const short8*)&gs[w][m][8 * q];
      const u16* w2p = pm2 + (size_t)ch * 6144;
      #pragma unroll
      for (int ct = 0; ct < 12; ++ct) {
        short8 bp = *(const short8*)(w2p + ct * 512);
        c2acc[ct] = __builtin_amdgcn_mfma_f32_16x16x32_bf16(ap, bp, c2acc[ct], 0, 0, 0);
      }
    }
  }

  // ---- epilogue: out = x1 + C2 + bias (C/D layout: row=q*4+r, col=ct*16+m) ----
  #pragma unroll
  for (int ct = 0; ct < 12; ++ct) {
    const int c = ct * 16 + m;
    const float bb = bm2[c];
    #pragma unroll
    for (int r = 0; r < 4; ++r) {
      const size_t idx = (tok0 + 16 * w + q * 4 + r) * 192 + c;
      io[idx] = c2acc[ct][r] + bb + io[idx];
    }
  }
}

extern "C" void kernel_launch(void* const* d_in, const int* in_sizes, int n_in,
                              void* d_out, int out_size, void* d_ws, size_t ws_size,
                              hipStream_t stream) {
  (void)in_sizes; (void)n_in; (void)out_size; (void)ws_size;
  const float* x    = (const float*)d_in[0];
  const float* n1g  = (const float*)d_in[1];
  const float* n1b  = (const float*)d_in[2];
  const float* qkvw = (const float*)d_in[3];
  const float* rpb  = (const float*)d_in[4];
  const float* pw   = (const float*)d_in[5];
  const float* pb   = (const float*)d_in[6];
  const float* n2g  = (const float*)d_in[7];
  const float* n2b  = (const float*)d_in[8];
  const float* w1   = (const float*)d_in[9];
  const float* bm1  = (const float*)d_in[10];
  const float* w2   = (const float*)d_in[11];
  const float* bm2  = (const float*)d_in[12];
  float* out = (float*)d_out;

  float* wsb  = (float*)((char*)d_ws + WSB_OFF);
  u16*   wsq  = (u16*)((char*)d_ws + WSQ_OFF);
  u16*   wsp  = (u16*)((char*)d_ws + WSP_OFF);
  u16*   wsm1 = (u16*)((char*)d_ws + WSM1_OFF);
  u16*   wsm2 = (u16*)((char*)d_ws + WSM2_OFF);

  hipLaunchKernelGGL(k_prep, dim3(192), dim3(256), 0, stream,
                     qkvw, pw, rpb, w1, w2, wsb, wsq, wsp, wsm1, wsm2);
  hipLaunchKernelGGL(k_attn, dim3(2048), dim3(256), 0, stream,
                     x, n1g, n1b, pb, wsb, wsq, wsp, out);
  hipLaunchKernelGGL(k_mlp, dim3(2048), dim3(256), 0, stream,
                     n2g, n2b, wsm1, bm1, wsm2, bm2, out);
}

// Round 4
// 503.867 us; speedup vs baseline: 1.3072x; 1.3072x over previous
//
#include <hip/hip_runtime.h>
#include <hip/hip_bf16.h>
#include <math.h>

typedef unsigned short u16;
typedef unsigned int u32;
typedef __attribute__((ext_vector_type(8))) short short8;
typedef __attribute__((ext_vector_type(4))) float floatx4;

__device__ __forceinline__ float bf2f(u16 u) { return __uint_as_float(((u32)u) << 16); }
__device__ __forceinline__ u16 f2bf(float f) {
  u32 u = __float_as_uint(f);
  u32 r = u + 0x7fffu + ((u >> 16) & 1u);
  return (u16)(r >> 16);
}

// workspace layout (bytes):
//   [0, 393216)          float wsb[4 cat][6 h][256 tid][16]    bias+mask frags
//   [393216, 614400)     u16   wsq[36 T][6 s][64 lane][8]      qkv weights, frag order
//   [614400, 688128)     u16   wsp[6 h][12 nt][64 lane][8]     proj weights, frag order
//   [688128, 983040)     u16   wsm1[24 ch][2 n][6 s][64][8]    mlp w1, frag order
//   [983040, 1277952)    u16   wsm2[24 ch][12 ct][64][8]       mlp w2, frag order
#define WSB_OFF  0
#define WSQ_OFF  393216
#define WSP_OFF  614400
#define WSM1_OFF 688128
#define WSM2_OFF 983040

// ---------------------------------------------------------------------------
// k_prep: one-time weight/bias repack into d_ws (idempotent, ~10us).
// ---------------------------------------------------------------------------
__global__ __launch_bounds__(256) void k_prep(
    const float* __restrict__ qkvw, const float* __restrict__ projw,
    const float* __restrict__ rpb,
    const float* __restrict__ w1, const float* __restrict__ w2,
    float* __restrict__ wsb, u16* __restrict__ wsq, u16* __restrict__ wsp,
    u16* __restrict__ wsm1, u16* __restrict__ wsm2)
{
  const int tid0 = blockIdx.x * 256 + threadIdx.x;
  const int NT = gridDim.x * 256;
  // qkv frags: T = mat*12 + h*2 + ct ; row = mat*192 + (h*2+ct)*16 + (lane&15)
  for (int idx = tid0; idx < 110592; idx += NT) {
    int e = idx & 7, lane = (idx >> 3) & 63, rest = idx >> 9;
    int s = rest % 6, T = rest / 6;
    int mat = T / 12, hct = T % 12;
    int row = mat * 192 + hct * 16 + (lane & 15);
    int col = 32 * s + 8 * (lane >> 4) + e;
    float v = qkvw[(size_t)row * 192 + col];
    if (mat == 0) v *= 0.1767766952966369f;   // fold q scale into Wq
    wsq[idx] = f2bf(v);
  }
  // proj frags: row = 16*nt + (lane&15) ; col = 32*h + 8*(lane>>4)+e
  for (int idx = tid0; idx < 36864; idx += NT) {
    int e = idx & 7, lane = (idx >> 3) & 63, rest = idx >> 9;
    int nt = rest % 12, h = rest / 12;
    int row = 16 * nt + (lane & 15);
    int col = 32 * h + 8 * (lane >> 4) + e;
    wsp[idx] = f2bf(projw[(size_t)row * 192 + col]);
  }
  // mlp w1 frags: rest = (ch*2+n)*6 + s ; row = ch*32 + n*16 + (lane&15)
  for (int idx = tid0; idx < 147456; idx += NT) {
    int e = idx & 7, lane = (idx >> 3) & 63, rest = idx >> 9;
    int s = rest % 6, t = rest / 6;
    int n = t & 1, ch = t >> 1;
    wsm1[idx] = f2bf(w1[(size_t)(ch * 32 + n * 16 + (lane & 15)) * 192
                        + 32 * s + 8 * (lane >> 4) + e]);
  }
  // mlp w2 frags: rest = ch*12 + ct ; row = ct*16 + (lane&15), col = ch*32+8q+e
  for (int idx = tid0; idx < 147456; idx += NT) {
    int e = idx & 7, lane = (idx >> 3) & 63, rest = idx >> 9;
    int ct = rest % 12, ch = rest / 12;
    wsm2[idx] = f2bf(w2[(size_t)(ct * 16 + (lane & 15)) * 768
                        + ch * 32 + 8 * (lane >> 4) + e]);
  }
  // bias+mask: idx = ((cat*6+h)*256 + tid)*16 + nt*4 + r
  for (int idx = tid0; idx < 98304; idx += NT) {
    int f16 = idx & 15; int nt = f16 >> 2, r = f16 & 3;
    int t = (idx >> 4) & 255; int rest = idx >> 12;
    int h = rest % 6, cat = rest / 6;
    int w = t >> 6, m = t & 15, ql = (t >> 4) & 3;
    int i = 16 * w + 4 * ql + r, j = 16 * nt + m;
    int ir = i >> 3, ic = i & 7, jr = j >> 3, jc = j & 7;
    float v = rpb[((ir - jr + 7) * 15 + (ic - jc + 7)) * 6 + h];
    int catH = cat >> 1, catW = cat & 1;
    int ci = (catH ? ((ir < 4) ? 1 : 2) : 0) * 3 + (catW ? ((ic < 4) ? 1 : 2) : 0);
    int cj = (catH ? ((jr < 4) ? 1 : 2) : 0) * 3 + (catW ? ((jc < 4) ? 1 : 2) : 0);
    if (ci != cj) v -= 100.f;
    wsb[idx] = v;
  }
}

// ---------------------------------------------------------------------------
// k_attn: LN1 + shifted-window attention + proj + residual. (unchanged)
// 2048 blocks x 256 threads (4 waves). 2 barriers per head.
// ---------------------------------------------------------------------------
__global__ __launch_bounds__(256) void k_attn(
    const float* __restrict__ x,
    const float* __restrict__ g1, const float* __restrict__ b1,
    const float* __restrict__ projb,
    const float* __restrict__ wsb, const u16* __restrict__ wsq,
    const u16* __restrict__ wsp,
    float* __restrict__ out)
{
  __shared__ __align__(16) u16 xn[64][200];   // LN1 out [token][ch]   25600 B
  __shared__ __align__(16) u16 qs[64][40];    // q (scaled)            5120 B
  __shared__ __align__(16) u16 ks[64][40];    // k                     5120 B
  __shared__ __align__(16) u16 vT[32][72];    // v^T [ch][token]       4608 B
  __shared__ __align__(16) u16 PO[4608];      // wave-private P/Oh     9216 B

  const int tid = threadIdx.x;
  const int blk = blockIdx.x;
  const int b  = blk >> 10;
  const int wh = (blk >> 5) & 31;
  const int ww = blk & 31;

  // ---- LN1 + gather (roll -4 folded into index); token-major bf16 ----
  {
    const int t = tid >> 2, l4 = tid & 3;
    const int rr = t >> 3, cc = t & 7;
    const int oh = (wh * 8 + rr + 4) & 255;
    const int ow = (ww * 8 + cc + 4) & 255;
    const float* px = x + (((size_t)b * 65536 + (size_t)oh * 256 + ow) * 192) + l4 * 48;
    float rv[48];
    float s = 0.f, ss = 0.f;
    const float4* p4 = (const float4*)px;
    #pragma unroll
    for (int i = 0; i < 12; ++i) {
      float4 v = p4[i];
      rv[i*4+0] = v.x; rv[i*4+1] = v.y; rv[i*4+2] = v.z; rv[i*4+3] = v.w;
      s  += v.x + v.y + v.z + v.w;
      ss += v.x*v.x + v.y*v.y + v.z*v.z + v.w*v.w;
    }
    s += __shfl_xor(s, 1);  s += __shfl_xor(s, 2);
    ss += __shfl_xor(ss, 1); ss += __shfl_xor(ss, 2);
    const float mean = s * (1.f / 192.f);
    const float var  = ss * (1.f / 192.f) - mean * mean;
    const float rstd = rsqrtf(var + 1e-5f);
    const int c0 = l4 * 48;
    #pragma unroll
    for (int i = 0; i < 12; ++i) {
      ushort4 o;
      o.x = f2bf((rv[i*4+0] - mean) * rstd * g1[c0+i*4+0] + b1[c0+i*4+0]);
      o.y = f2bf((rv[i*4+1] - mean) * rstd * g1[c0+i*4+1] + b1[c0+i*4+1]);
      o.z = f2bf((rv[i*4+2] - mean) * rstd * g1[c0+i*4+2] + b1[c0+i*4+2]);
      o.w = f2bf((rv[i*4+3] - mean) * rstd * g1[c0+i*4+3] + b1[c0+i*4+3]);
      *(ushort4*)&xn[t][c0 + i*4] = o;
    }
  }

  const int w    = tid >> 6;         // wave id
  const int lane = tid & 63;
  const int m    = tid & 15;
  const int ql   = (tid >> 4) & 3;
  const int ct   = w >> 1;           // channel tile (0: ch 0-15, 1: ch 16-31)
  const int tb   = (w & 1) * 2;      // token-tile base (0 or 2)
  const int cat  = ((wh == 31) ? 2 : 0) | ((ww == 31) ? 1 : 0);
  const float* pbias = wsb + ((size_t)(cat * 6) * 256 + tid) * 16;
  const int po = w * 1152;           // this wave's private PO region (u16 idx)

  floatx4 acc[12];
  #pragma unroll
  for (int nt = 0; nt < 12; ++nt) acc[nt] = (floatx4){0.f, 0.f, 0.f, 0.f};

  __syncthreads();

  #pragma unroll 1
  for (int h = 0; h < 6; ++h) {
    // ---- QKV: wave computes (q,k,v) x (2 token-tiles) for its ch-tile ----
    {
      const u16* wqp = wsq + (size_t)(h * 2 + ct) * 3072 + lane * 8;
      floatx4 dq[2], dk[2], dv[2];
      #pragma unroll
      for (int t = 0; t < 2; ++t) {
        dq[t] = (floatx4){0.f,0.f,0.f,0.f};
        dk[t] = (floatx4){0.f,0.f,0.f,0.f};
        dv[t] = (floatx4){0.f,0.f,0.f,0.f};
      }
      #pragma unroll
      for (int s = 0; s < 6; ++s) {
        short8 a0 = *(const short8*)&xn[16*tb + m][32*s + 8*ql];
        short8 a1 = *(const short8*)&xn[16*tb + 16 + m][32*s + 8*ql];
        short8 bq = *(const short8*)(wqp + s*512);
        short8 bk = *(const short8*)(wqp + 36864 + s*512);
        short8 bv = *(const short8*)(wqp + 73728 + s*512);
        dq[0] = __builtin_amdgcn_mfma_f32_16x16x32_bf16(a0, bq, dq[0], 0, 0, 0);
        dq[1] = __builtin_amdgcn_mfma_f32_16x16x32_bf16(a1, bq, dq[1], 0, 0, 0);
        dk[0] = __builtin_amdgcn_mfma_f32_16x16x32_bf16(a0, bk, dk[0], 0, 0, 0);
        dk[1] = __builtin_amdgcn_mfma_f32_16x16x32_bf16(a1, bk, dk[1], 0, 0, 0);
        dv[0] = __builtin_amdgcn_mfma_f32_16x16x32_bf16(a0, bv, dv[0], 0, 0, 0);
        dv[1] = __builtin_amdgcn_mfma_f32_16x16x32_bf16(a1, bv, dv[1], 0, 0, 0);
      }
      #pragma unroll
      for (int t = 0; t < 2; ++t) {
        #pragma unroll
        for (int r = 0; r < 4; ++r) {
          qs[16*(tb+t) + 4*ql + r][ct*16 + m] = f2bf(dq[t][r]);
          ks[16*(tb+t) + 4*ql + r][ct*16 + m] = f2bf(dk[t][r]);
        }
        ushort4 o;
        o.x = f2bf(dv[t][0]); o.y = f2bf(dv[t][1]);
        o.z = f2bf(dv[t][2]); o.w = f2bf(dv[t][3]);
        *(ushort4*)&vT[ct*16 + m][16*(tb+t) + 4*ql] = o;
      }
    }
    __syncthreads();                 // bar1: q/k/vT ready

    // ---- S = q.k^T + (bias+mask as C-operand); softmax in-register ----
    floatx4 sf[4];
    {
      short8 aq = *(const short8*)&qs[16*w + m][8*ql];
      const float* pb = pbias + (size_t)h * 4096;
      #pragma unroll
      for (int nt = 0; nt < 4; ++nt) {
        float4 b4 = *(const float4*)(pb + nt*4);
        short8 bk = *(const short8*)&ks[16*nt + m][8*ql];
        sf[nt] = __builtin_amdgcn_mfma_f32_16x16x32_bf16(
            aq, bk, (floatx4){b4.x, b4.y, b4.z, b4.w}, 0, 0, 0);
      }
    }
    {
      float mxr[4] = {-3.0e38f, -3.0e38f, -3.0e38f, -3.0e38f};
      #pragma unroll
      for (int nt = 0; nt < 4; ++nt)
        #pragma unroll
        for (int r = 0; r < 4; ++r) mxr[r] = fmaxf(mxr[r], sf[nt][r]);
      #pragma unroll
      for (int d = 1; d <= 8; d <<= 1)
        #pragma unroll
        for (int r = 0; r < 4; ++r) mxr[r] = fmaxf(mxr[r], __shfl_xor(mxr[r], d));
      float smr[4] = {0.f, 0.f, 0.f, 0.f};
      #pragma unroll
      for (int nt = 0; nt < 4; ++nt)
        #pragma unroll
        for (int r = 0; r < 4; ++r) {
          float e = __expf(sf[nt][r] - mxr[r]);
          sf[nt][r] = e;
          smr[r] += e;
        }
      #pragma unroll
      for (int d = 1; d <= 8; d <<= 1)
        #pragma unroll
        for (int r = 0; r < 4; ++r) smr[r] += __shfl_xor(smr[r], d);
      // write P (wave-private; in-order same-wave DS, no barrier)
      #pragma unroll
      for (int r = 0; r < 4; ++r) {
        const float inv = 1.f / smr[r];
        #pragma unroll
        for (int nt = 0; nt < 4; ++nt)
          PO[po + (4*ql + r)*72 + 16*nt + m] = f2bf(sf[nt][r] * inv);
      }
    }

    // ---- PV: O[tok][ch] = P[16 tok x 64] @ vT[32 ch x 64]^T ----
    floatx4 of[2];
    of[0] = (floatx4){0.f,0.f,0.f,0.f}; of[1] = (floatx4){0.f,0.f,0.f,0.f};
    #pragma unroll
    for (int s = 0; s < 2; ++s) {
      short8 ap = *(const short8*)&PO[po + m*72 + 32*s + 8*ql];
      #pragma unroll
      for (int mt = 0; mt < 2; ++mt) {
        short8 bv = *(const short8*)&vT[16*mt + m][32*s + 8*ql];
        of[mt] = __builtin_amdgcn_mfma_f32_16x16x32_bf16(ap, bv, of[mt], 0, 0, 0);
      }
    }
    __syncthreads();                 // bar2: shared q/k/vT reads done

    // ---- Oh (wave-private, overlays P) + proj accumulate ----
    #pragma unroll
    for (int mt = 0; mt < 2; ++mt)
      #pragma unroll
      for (int r = 0; r < 4; ++r)
        PO[po + (4*ql + r)*40 + 16*mt + m] = f2bf(of[mt][r]);
    {
      short8 ao = *(const short8*)&PO[po + m*40 + 8*ql];
      const u16* wpp = wsp + (size_t)h * 6144 + lane * 8;
      #pragma unroll
      for (int nt = 0; nt < 12; ++nt) {
        short8 bw = *(const short8*)(wpp + nt*512);
        acc[nt] = __builtin_amdgcn_mfma_f32_16x16x32_bf16(ao, bw, acc[nt], 0, 0, 0);
      }
    }
  }

  // ---- epilogue: out = x + proj + projb (window-reverse + roll via gather) ----
  {
    size_t rbase[4];
    #pragma unroll
    for (int r = 0; r < 4; ++r) {
      const int i  = 16*w + 4*ql + r;
      const int ir = i >> 3, ic = i & 7;
      const int oh = (wh * 8 + ir + 4) & 255;
      const int ow = (ww * 8 + ic + 4) & 255;
      rbase[r] = ((size_t)b * 65536 + (size_t)oh * 256 + ow) * 192;
    }
    #pragma unroll
    for (int nt = 0; nt < 12; ++nt) {
      const int c = 16*nt + m;
      const float pb = projb[c];
      #pragma unroll
      for (int r = 0; r < 4; ++r) {
        const size_t idx = rbase[r] + c;
        out[idx] = x[idx] + acc[nt][r] + pb;
      }
    }
  }
}

// ---------------------------------------------------------------------------
// k_mlp v3: LN2 + MLP(GELU) + residual, in-place on d_out.
// Pre-packed bf16 B-fragments + double-buffered LDS staging (pure copy,
// register-prefetched, ONE barrier per chunk). LDS 79872 B -> 2 blocks/CU.
// ---------------------------------------------------------------------------
__global__ __launch_bounds__(256) void k_mlp(
    const float* __restrict__ g2, const float* __restrict__ b2,
    const u16* __restrict__ wsm1, const float* __restrict__ bm1,
    const u16* __restrict__ wsm2, const float* __restrict__ bm2,
    float* __restrict__ io)
{
  __shared__ u16 xn[64][200];              // LN2 out, bf16 [token][ch] (25600 B)
  __shared__ u16 gs[4][16][40];            // gelu(H) wave-private      (5120 B)
  __shared__ __align__(16) u16 wbuf[2][12288];  // dbuf: w1[0:6144]|w2[6144:12288] (49152 B)

  const int tid = threadIdx.x;
  const size_t tok0 = (size_t)blockIdx.x * 64;

  // ---- LN2 (4 threads / token) -> xn bf16 ----
  {
    const int t = tid >> 2, l4 = tid & 3;
    const float* px = io + (tok0 + t) * 192 + l4 * 48;
    float rv[48];
    float s = 0.f, ss = 0.f;
    const float4* p4 = (const float4*)px;
    #pragma unroll
    for (int i = 0; i < 12; ++i) {
      float4 v = p4[i];
      rv[i*4+0] = v.x; rv[i*4+1] = v.y; rv[i*4+2] = v.z; rv[i*4+3] = v.w;
      s += v.x + v.y + v.z + v.w;
      ss += v.x*v.x + v.y*v.y + v.z*v.z + v.w*v.w;
    }
    s += __shfl_xor(s, 1);  s += __shfl_xor(s, 2);
    ss += __shfl_xor(ss, 1); ss += __shfl_xor(ss, 2);
    const float mean = s * (1.f / 192.f);
    const float var  = ss * (1.f / 192.f) - mean * mean;
    const float rstd = rsqrtf(var + 1e-5f);
    const int c0 = l4 * 48;
    #pragma unroll
    for (int i = 0; i < 12; ++i) {
      ushort4 o;
      o.x = f2bf((rv[i*4+0] - mean) * rstd * g2[c0+i*4+0] + b2[c0+i*4+0]);
      o.y = f2bf((rv[i*4+1] - mean) * rstd * g2[c0+i*4+1] + b2[c0+i*4+1]);
      o.z = f2bf((rv[i*4+2] - mean) * rstd * g2[c0+i*4+2] + b2[c0+i*4+2]);
      o.w = f2bf((rv[i*4+3] - mean) * rstd * g2[c0+i*4+3] + b2[c0+i*4+3]);
      *(ushort4*)&xn[t][c0 + i*4] = o;
    }
  }

  const int w = tid >> 6;          // wave: owns tokens [16w,16w+16)
  const int lane = tid & 63;
  const int m = lane & 15;
  const int q = lane >> 4;

  floatx4 c2acc[12];
  #pragma unroll
  for (int ct = 0; ct < 12; ++ct) c2acc[ct] = (floatx4){0.f, 0.f, 0.f, 0.f};

  // staging: per chunk 12288 u16 (w1: 6144, w2: 6144) = 6 x short8 per thread
  short8 pf1[3], pf2[3];
  auto stage = [&](int ch) {
    const u16* p1 = wsm1 + (size_t)ch * 6144;
    const u16* p2 = wsm2 + (size_t)ch * 6144;
    #pragma unroll
    for (int it = 0; it < 3; ++it) {
      pf1[it] = *(const short8*)(p1 + (it * 256 + tid) * 8);
      pf2[it] = *(const short8*)(p2 + (it * 256 + tid) * 8);
    }
  };
  auto commit = [&](int buf) {
    #pragma unroll
    for (int it = 0; it < 3; ++it) {
      *(short8*)&wbuf[buf][(it * 256 + tid) * 8] = pf1[it];
      *(short8*)&wbuf[buf][6144 + (it * 256 + tid) * 8] = pf2[it];
    }
  };

  stage(0);
  commit(0);
  __syncthreads();                 // xn + wbuf[0] ready

  // A-fragments are chunk-invariant: hoist once (24 VGPRs)
  short8 a_all[6];
  #pragma unroll
  for (int s = 0; s < 6; ++s)
    a_all[s] = *(const short8*)&xn[16 * w + m][32 * s + 8 * q];

  #pragma unroll 1
  for (int ch = 0; ch < 24; ++ch) {
    const int buf = ch & 1;
    if (ch + 1 < 24) stage(ch + 1);     // loads in flight during compute

    // GEMM1: H tile 16x32, K=192 (6 ksteps) from LDS
    const u16* w1p = &wbuf[buf][lane * 8];
    floatx4 h0 = (floatx4){0.f, 0.f, 0.f, 0.f};
    floatx4 h1 = (floatx4){0.f, 0.f, 0.f, 0.f};
    #pragma unroll
    for (int s = 0; s < 6; ++s) {
      short8 b0 = *(const short8*)(w1p + s * 512);
      short8 b1 = *(const short8*)(w1p + 3072 + s * 512);
      h0 = __builtin_amdgcn_mfma_f32_16x16x32_bf16(a_all[s], b0, h0, 0, 0, 0);
      h1 = __builtin_amdgcn_mfma_f32_16x16x32_bf16(a_all[s], b1, h1, 0, 0, 0);
    }

    // bias + exact GELU, wave-private LDS transpose (no barrier needed)
    const int c0 = ch * 32;
    {
      const float bb0 = bm1[c0 + m];
      const float bb1 = bm1[c0 + 16 + m];
      #pragma unroll
      for (int r = 0; r < 4; ++r) {
        float v0 = h0[r] + bb0;
        float v1 = h1[r] + bb1;
        float g0 = 0.5f * v0 * (1.f + erff(v0 * 0.70710678118654752f));
        float g1 = 0.5f * v1 * (1.f + erff(v1 * 0.70710678118654752f));
        gs[w][q * 4 + r][m] = f2bf(g0);
        gs[w][q * 4 + r][16 + m] = f2bf(g1);
      }
    }

    // GEMM2: C2[16x192] += G[16x32] @ w2chunk, K=32 (1 kstep) from LDS
    {
      short8 ap = *(const short8*)&gs[w][m][8 * q];
      const u16* w2p = &wbuf[buf][6144 + lane * 8];
      #pragma unroll
      for (int ct = 0; ct < 12; ++ct) {
        short8 bp = *(const short8*)(w2p + ct * 512);
        c2acc[ct] = __builtin_amdgcn_mfma_f32_16x16x32_bf16(ap, bp, c2acc[ct], 0, 0, 0);
      }
    }

    if (ch + 1 < 24) {
      commit(buf ^ 1);             // other buffer: free since end of chunk ch-1
      __syncthreads();             // wbuf[buf^1] staged for next chunk
    }
  }

  // ---- epilogue: out = x1 + C2 + bias (C/D layout: row=q*4+r, col=ct*16+m) ----
  #pragma unroll
  for (int ct = 0; ct < 12; ++ct) {
    const int c = ct * 16 + m;
    const float bb = bm2[c];
    #pragma unroll
    for (int r = 0; r < 4; ++r) {
      const size_t idx = (tok0 + 16 * w + q * 4 + r) * 192 + c;
      io[idx] = c2acc[ct][r] + bb + io[idx];
    }
  }
}

extern "C" void kernel_launch(void* const* d_in, const int* in_sizes, int n_in,
                              void* d_out, int out_size, void* d_ws, size_t ws_size,
                              hipStream_t stream) {
  (void)in_sizes; (void)n_in; (void)out_size; (void)ws_size;
  const float* x    = (const float*)d_in[0];
  const float* n1g  = (const float*)d_in[1];
  const float* n1b  = (const float*)d_in[2];
  const float* qkvw = (const float*)d_in[3];
  const float* rpb  = (const float*)d_in[4];
  const float* pw   = (const float*)d_in[5];
  const float* pb   = (const float*)d_in[6];
  const float* n2g  = (const float*)d_in[7];
  const float* n2b  = (const float*)d_in[8];
  const float* w1   = (const float*)d_in[9];
  const float* bm1  = (const float*)d_in[10];
  const float* w2   = (const float*)d_in[11];
  const float* bm2  = (const float*)d_in[12];
  float* out = (float*)d_out;

  float* wsb  = (float*)((char*)d_ws + WSB_OFF);
  u16*   wsq  = (u16*)((char*)d_ws + WSQ_OFF);
  u16*   wsp  = (u16*)((char*)d_ws + WSP_OFF);
  u16*   wsm1 = (u16*)((char*)d_ws + WSM1_OFF);
  u16*   wsm2 = (u16*)((char*)d_ws + WSM2_OFF);

  hipLaunchKernelGGL(k_prep, dim3(192), dim3(256), 0, stream,
                     qkvw, pw, rpb, w1, w2, wsb, wsq, wsp, wsm1, wsm2);
  hipLaunchKernelGGL(k_attn, dim3(2048), dim3(256), 0, stream,
                     x, n1g, n1b, pb, wsb, wsq, wsp, out);
  hipLaunchKernelGGL(k_mlp, dim3(2048), dim3(256), 0, stream,
                     n2g, n2b, wsm1, bm1, wsm2, bm2, out);
}

// Round 5
// 498.111 us; speedup vs baseline: 1.3223x; 1.0116x over previous
//
#include <hip/hip_runtime.h>
#include <hip/hip_bf16.h>
#include <math.h>

typedef unsigned short u16;
typedef unsigned int u32;
typedef __attribute__((ext_vector_type(8))) short short8;
typedef __attribute__((ext_vector_type(4))) float floatx4;

__device__ __forceinline__ float bf2f(u16 u) { return __uint_as_float(((u32)u) << 16); }
__device__ __forceinline__ u16 f2bf(float f) {
  u32 u = __float_as_uint(f);
  u32 r = u + 0x7fffu + ((u >> 16) & 1u);
  return (u16)(r >> 16);
}

// workspace layout (bytes):
//   [0, 393216)          float wsb[4 cat][6 h][256 tid][16]    bias+mask frags
//   [393216, 614400)     u16   wsq[36 T][6 s][64 lane][8]      qkv weights, frag order
//   [614400, 688128)     u16   wsp[6 h][12 nt][64 lane][8]     proj weights, frag order
//   [688128, 983040)     u16   wsm1[24 ch][2 n][6 s][64][8]    mlp w1, frag order
//   [983040, 1277952)    u16   wsm2[24 ch][12 ct][64][8]       mlp w2, frag order
#define WSB_OFF  0
#define WSQ_OFF  393216
#define WSP_OFF  614400
#define WSM1_OFF 688128
#define WSM2_OFF 983040

// ---------------------------------------------------------------------------
// k_prep: one-time weight/bias repack into d_ws (idempotent, ~10us).
// ---------------------------------------------------------------------------
__global__ __launch_bounds__(256) void k_prep(
    const float* __restrict__ qkvw, const float* __restrict__ projw,
    const float* __restrict__ rpb,
    const float* __restrict__ w1, const float* __restrict__ w2,
    float* __restrict__ wsb, u16* __restrict__ wsq, u16* __restrict__ wsp,
    u16* __restrict__ wsm1, u16* __restrict__ wsm2)
{
  const int tid0 = blockIdx.x * 256 + threadIdx.x;
  const int NT = gridDim.x * 256;
  // qkv frags: T = mat*12 + h*2 + ct ; row = mat*192 + (h*2+ct)*16 + (lane&15)
  for (int idx = tid0; idx < 110592; idx += NT) {
    int e = idx & 7, lane = (idx >> 3) & 63, rest = idx >> 9;
    int s = rest % 6, T = rest / 6;
    int mat = T / 12, hct = T % 12;
    int row = mat * 192 + hct * 16 + (lane & 15);
    int col = 32 * s + 8 * (lane >> 4) + e;
    float v = qkvw[(size_t)row * 192 + col];
    if (mat == 0) v *= 0.1767766952966369f;   // fold q scale into Wq
    wsq[idx] = f2bf(v);
  }
  // proj frags: row = 16*nt + (lane&15) ; col = 32*h + 8*(lane>>4)+e
  for (int idx = tid0; idx < 36864; idx += NT) {
    int e = idx & 7, lane = (idx >> 3) & 63, rest = idx >> 9;
    int nt = rest % 12, h = rest / 12;
    int row = 16 * nt + (lane & 15);
    int col = 32 * h + 8 * (lane >> 4) + e;
    wsp[idx] = f2bf(projw[(size_t)row * 192 + col]);
  }
  // mlp w1 frags: rest = (ch*2+n)*6 + s ; row = ch*32 + n*16 + (lane&15)
  for (int idx = tid0; idx < 147456; idx += NT) {
    int e = idx & 7, lane = (idx >> 3) & 63, rest = idx >> 9;
    int s = rest % 6, t = rest / 6;
    int n = t & 1, ch = t >> 1;
    wsm1[idx] = f2bf(w1[(size_t)(ch * 32 + n * 16 + (lane & 15)) * 192
                        + 32 * s + 8 * (lane >> 4) + e]);
  }
  // mlp w2 frags: rest = ch*12 + ct ; row = ct*16 + (lane&15), col = ch*32+8q+e
  for (int idx = tid0; idx < 147456; idx += NT) {
    int e = idx & 7, lane = (idx >> 3) & 63, rest = idx >> 9;
    int ct = rest % 12, ch = rest / 12;
    wsm2[idx] = f2bf(w2[(size_t)(ct * 16 + (lane & 15)) * 768
                        + ch * 32 + 8 * (lane >> 4) + e]);
  }
  // bias+mask: idx = ((cat*6+h)*256 + tid)*16 + nt*4 + r
  for (int idx = tid0; idx < 98304; idx += NT) {
    int f16 = idx & 15; int nt = f16 >> 2, r = f16 & 3;
    int t = (idx >> 4) & 255; int rest = idx >> 12;
    int h = rest % 6, cat = rest / 6;
    int w = t >> 6, m = t & 15, ql = (t >> 4) & 3;
    int i = 16 * w + 4 * ql + r, j = 16 * nt + m;
    int ir = i >> 3, ic = i & 7, jr = j >> 3, jc = j & 7;
    float v = rpb[((ir - jr + 7) * 15 + (ic - jc + 7)) * 6 + h];
    int catH = cat >> 1, catW = cat & 1;
    int ci = (catH ? ((ir < 4) ? 1 : 2) : 0) * 3 + (catW ? ((ic < 4) ? 1 : 2) : 0);
    int cj = (catH ? ((jr < 4) ? 1 : 2) : 0) * 3 + (catW ? ((jc < 4) ? 1 : 2) : 0);
    if (ci != cj) v -= 100.f;
    wsb[idx] = v;
  }
}

// ---------------------------------------------------------------------------
// k_attn: LN1 + shifted-window attention + proj + residual. (unchanged)
// 2048 blocks x 256 threads (4 waves). 2 barriers per head.
// ---------------------------------------------------------------------------
__global__ __launch_bounds__(256) void k_attn(
    const float* __restrict__ x,
    const float* __restrict__ g1, const float* __restrict__ b1,
    const float* __restrict__ projb,
    const float* __restrict__ wsb, const u16* __restrict__ wsq,
    const u16* __restrict__ wsp,
    float* __restrict__ out)
{
  __shared__ __align__(16) u16 xn[64][200];   // LN1 out [token][ch]   25600 B
  __shared__ __align__(16) u16 qs[64][40];    // q (scaled)            5120 B
  __shared__ __align__(16) u16 ks[64][40];    // k                     5120 B
  __shared__ __align__(16) u16 vT[32][72];    // v^T [ch][token]       4608 B
  __shared__ __align__(16) u16 PO[4608];      // wave-private P/Oh     9216 B

  const int tid = threadIdx.x;
  const int blk = blockIdx.x;
  const int b  = blk >> 10;
  const int wh = (blk >> 5) & 31;
  const int ww = blk & 31;

  // ---- LN1 + gather (roll -4 folded into index); token-major bf16 ----
  {
    const int t = tid >> 2, l4 = tid & 3;
    const int rr = t >> 3, cc = t & 7;
    const int oh = (wh * 8 + rr + 4) & 255;
    const int ow = (ww * 8 + cc + 4) & 255;
    const float* px = x + (((size_t)b * 65536 + (size_t)oh * 256 + ow) * 192) + l4 * 48;
    float rv[48];
    float s = 0.f, ss = 0.f;
    const float4* p4 = (const float4*)px;
    #pragma unroll
    for (int i = 0; i < 12; ++i) {
      float4 v = p4[i];
      rv[i*4+0] = v.x; rv[i*4+1] = v.y; rv[i*4+2] = v.z; rv[i*4+3] = v.w;
      s  += v.x + v.y + v.z + v.w;
      ss += v.x*v.x + v.y*v.y + v.z*v.z + v.w*v.w;
    }
    s += __shfl_xor(s, 1);  s += __shfl_xor(s, 2);
    ss += __shfl_xor(ss, 1); ss += __shfl_xor(ss, 2);
    const float mean = s * (1.f / 192.f);
    const float var  = ss * (1.f / 192.f) - mean * mean;
    const float rstd = rsqrtf(var + 1e-5f);
    const int c0 = l4 * 48;
    #pragma unroll
    for (int i = 0; i < 12; ++i) {
      ushort4 o;
      o.x = f2bf((rv[i*4+0] - mean) * rstd * g1[c0+i*4+0] + b1[c0+i*4+0]);
      o.y = f2bf((rv[i*4+1] - mean) * rstd * g1[c0+i*4+1] + b1[c0+i*4+1]);
      o.z = f2bf((rv[i*4+2] - mean) * rstd * g1[c0+i*4+2] + b1[c0+i*4+2]);
      o.w = f2bf((rv[i*4+3] - mean) * rstd * g1[c0+i*4+3] + b1[c0+i*4+3]);
      *(ushort4*)&xn[t][c0 + i*4] = o;
    }
  }

  const int w    = tid >> 6;         // wave id
  const int lane = tid & 63;
  const int m    = tid & 15;
  const int ql   = (tid >> 4) & 3;
  const int ct   = w >> 1;           // channel tile (0: ch 0-15, 1: ch 16-31)
  const int tb   = (w & 1) * 2;      // token-tile base (0 or 2)
  const int cat  = ((wh == 31) ? 2 : 0) | ((ww == 31) ? 1 : 0);
  const float* pbias = wsb + ((size_t)(cat * 6) * 256 + tid) * 16;
  const int po = w * 1152;           // this wave's private PO region (u16 idx)

  floatx4 acc[12];
  #pragma unroll
  for (int nt = 0; nt < 12; ++nt) acc[nt] = (floatx4){0.f, 0.f, 0.f, 0.f};

  __syncthreads();

  #pragma unroll 1
  for (int h = 0; h < 6; ++h) {
    // ---- QKV: wave computes (q,k,v) x (2 token-tiles) for its ch-tile ----
    {
      const u16* wqp = wsq + (size_t)(h * 2 + ct) * 3072 + lane * 8;
      floatx4 dq[2], dk[2], dv[2];
      #pragma unroll
      for (int t = 0; t < 2; ++t) {
        dq[t] = (floatx4){0.f,0.f,0.f,0.f};
        dk[t] = (floatx4){0.f,0.f,0.f,0.f};
        dv[t] = (floatx4){0.f,0.f,0.f,0.f};
      }
      #pragma unroll
      for (int s = 0; s < 6; ++s) {
        short8 a0 = *(const short8*)&xn[16*tb + m][32*s + 8*ql];
        short8 a1 = *(const short8*)&xn[16*tb + 16 + m][32*s + 8*ql];
        short8 bq = *(const short8*)(wqp + s*512);
        short8 bk = *(const short8*)(wqp + 36864 + s*512);
        short8 bv = *(const short8*)(wqp + 73728 + s*512);
        dq[0] = __builtin_amdgcn_mfma_f32_16x16x32_bf16(a0, bq, dq[0], 0, 0, 0);
        dq[1] = __builtin_amdgcn_mfma_f32_16x16x32_bf16(a1, bq, dq[1], 0, 0, 0);
        dk[0] = __builtin_amdgcn_mfma_f32_16x16x32_bf16(a0, bk, dk[0], 0, 0, 0);
        dk[1] = __builtin_amdgcn_mfma_f32_16x16x32_bf16(a1, bk, dk[1], 0, 0, 0);
        dv[0] = __builtin_amdgcn_mfma_f32_16x16x32_bf16(a0, bv, dv[0], 0, 0, 0);
        dv[1] = __builtin_amdgcn_mfma_f32_16x16x32_bf16(a1, bv, dv[1], 0, 0, 0);
      }
      #pragma unroll
      for (int t = 0; t < 2; ++t) {
        #pragma unroll
        for (int r = 0; r < 4; ++r) {
          qs[16*(tb+t) + 4*ql + r][ct*16 + m] = f2bf(dq[t][r]);
          ks[16*(tb+t) + 4*ql + r][ct*16 + m] = f2bf(dk[t][r]);
        }
        ushort4 o;
        o.x = f2bf(dv[t][0]); o.y = f2bf(dv[t][1]);
        o.z = f2bf(dv[t][2]); o.w = f2bf(dv[t][3]);
        *(ushort4*)&vT[ct*16 + m][16*(tb+t) + 4*ql] = o;
      }
    }
    __syncthreads();                 // bar1: q/k/vT ready

    // ---- S = q.k^T + (bias+mask as C-operand); softmax in-register ----
    floatx4 sf[4];
    {
      short8 aq = *(const short8*)&qs[16*w + m][8*ql];
      const float* pb = pbias + (size_t)h * 4096;
      #pragma unroll
      for (int nt = 0; nt < 4; ++nt) {
        float4 b4 = *(const float4*)(pb + nt*4);
        short8 bk = *(const short8*)&ks[16*nt + m][8*ql];
        sf[nt] = __builtin_amdgcn_mfma_f32_16x16x32_bf16(
            aq, bk, (floatx4){b4.x, b4.y, b4.z, b4.w}, 0, 0, 0);
      }
    }
    {
      float mxr[4] = {-3.0e38f, -3.0e38f, -3.0e38f, -3.0e38f};
      #pragma unroll
      for (int nt = 0; nt < 4; ++nt)
        #pragma unroll
        for (int r = 0; r < 4; ++r) mxr[r] = fmaxf(mxr[r], sf[nt][r]);
      #pragma unroll
      for (int d = 1; d <= 8; d <<= 1)
        #pragma unroll
        for (int r = 0; r < 4; ++r) mxr[r] = fmaxf(mxr[r], __shfl_xor(mxr[r], d));
      float smr[4] = {0.f, 0.f, 0.f, 0.f};
      #pragma unroll
      for (int nt = 0; nt < 4; ++nt)
        #pragma unroll
        for (int r = 0; r < 4; ++r) {
          float e = __expf(sf[nt][r] - mxr[r]);
          sf[nt][r] = e;
          smr[r] += e;
        }
      #pragma unroll
      for (int d = 1; d <= 8; d <<= 1)
        #pragma unroll
        for (int r = 0; r < 4; ++r) smr[r] += __shfl_xor(smr[r], d);
      // write P (wave-private; in-order same-wave DS, no barrier)
      #pragma unroll
      for (int r = 0; r < 4; ++r) {
        const float inv = 1.f / smr[r];
        #pragma unroll
        for (int nt = 0; nt < 4; ++nt)
          PO[po + (4*ql + r)*72 + 16*nt + m] = f2bf(sf[nt][r] * inv);
      }
    }

    // ---- PV: O[tok][ch] = P[16 tok x 64] @ vT[32 ch x 64]^T ----
    floatx4 of[2];
    of[0] = (floatx4){0.f,0.f,0.f,0.f}; of[1] = (floatx4){0.f,0.f,0.f,0.f};
    #pragma unroll
    for (int s = 0; s < 2; ++s) {
      short8 ap = *(const short8*)&PO[po + m*72 + 32*s + 8*ql];
      #pragma unroll
      for (int mt = 0; mt < 2; ++mt) {
        short8 bv = *(const short8*)&vT[16*mt + m][32*s + 8*ql];
        of[mt] = __builtin_amdgcn_mfma_f32_16x16x32_bf16(ap, bv, of[mt], 0, 0, 0);
      }
    }
    __syncthreads();                 // bar2: shared q/k/vT reads done

    // ---- Oh (wave-private, overlays P) + proj accumulate ----
    #pragma unroll
    for (int mt = 0; mt < 2; ++mt)
      #pragma unroll
      for (int r = 0; r < 4; ++r)
        PO[po + (4*ql + r)*40 + 16*mt + m] = f2bf(of[mt][r]);
    {
      short8 ao = *(const short8*)&PO[po + m*40 + 8*ql];
      const u16* wpp = wsp + (size_t)h * 6144 + lane * 8;
      #pragma unroll
      for (int nt = 0; nt < 12; ++nt) {
        short8 bw = *(const short8*)(wpp + nt*512);
        acc[nt] = __builtin_amdgcn_mfma_f32_16x16x32_bf16(ao, bw, acc[nt], 0, 0, 0);
      }
    }
  }

  // ---- epilogue: out = x + proj + projb (window-reverse + roll via gather) ----
  {
    size_t rbase[4];
    #pragma unroll
    for (int r = 0; r < 4; ++r) {
      const int i  = 16*w + 4*ql + r;
      const int ir = i >> 3, ic = i & 7;
      const int oh = (wh * 8 + ir + 4) & 255;
      const int ow = (ww * 8 + ic + 4) & 255;
      rbase[r] = ((size_t)b * 65536 + (size_t)oh * 256 + ow) * 192;
    }
    #pragma unroll
    for (int nt = 0; nt < 12; ++nt) {
      const int c = 16*nt + m;
      const float pb = projb[c];
      #pragma unroll
      for (int r = 0; r < 4; ++r) {
        const size_t idx = rbase[r] + c;
        out[idx] = x[idx] + acc[nt][r] + pb;
      }
    }
  }
}

// ---------------------------------------------------------------------------
// k_mlp v4: LN2 + MLP(GELU) + residual, in-place on d_out.
// LDS 30720 B: xn region (25600 B) is OVERLAID by the w1 double-buffer
// (2x12288 B) after the A-fragment register hoist. w2 B-frags are loaded
// straight from L2 into registers at chunk top (12 independent MFMAs ->
// latency hides under GEMM1+GELU). One barrier per chunk.
// ---------------------------------------------------------------------------
__global__ __launch_bounds__(256) void k_mlp(
    const float* __restrict__ g2, const float* __restrict__ b2,
    const u16* __restrict__ wsm1, const float* __restrict__ bm1,
    const u16* __restrict__ wsm2, const float* __restrict__ bm2,
    float* __restrict__ io)
{
  __shared__ __align__(16) u16 shbuf[12800];   // xn[64][200] overlay wbuf[2][6144]
  __shared__ u16 gs[4][16][40];                // gelu(H) wave-private (5120 B)

  const int tid = threadIdx.x;
  const size_t tok0 = (size_t)blockIdx.x * 64;

  const int w = tid >> 6;          // wave: owns tokens [16w,16w+16)
  const int lane = tid & 63;
  const int m = lane & 15;
  const int q = lane >> 4;

  // stage chunk-0 w1 into registers early (in flight during LN2)
  short8 pf1[3];
  {
    const u16* p1 = wsm1;
    #pragma unroll
    for (int it = 0; it < 3; ++it)
      pf1[it] = *(const short8*)(p1 + (it * 256 + tid) * 8);
  }

  // ---- LN2 (4 threads / token) -> xn bf16 (in shbuf) ----
  {
    const int t = tid >> 2, l4 = tid & 3;
    const float* px = io + (tok0 + t) * 192 + l4 * 48;
    float rv[48];
    float s = 0.f, ss = 0.f;
    const float4* p4 = (const float4*)px;
    #pragma unroll
    for (int i = 0; i < 12; ++i) {
      float4 v = p4[i];
      rv[i*4+0] = v.x; rv[i*4+1] = v.y; rv[i*4+2] = v.z; rv[i*4+3] = v.w;
      s += v.x + v.y + v.z + v.w;
      ss += v.x*v.x + v.y*v.y + v.z*v.z + v.w*v.w;
    }
    s += __shfl_xor(s, 1);  s += __shfl_xor(s, 2);
    ss += __shfl_xor(ss, 1); ss += __shfl_xor(ss, 2);
    const float mean = s * (1.f / 192.f);
    const float var  = ss * (1.f / 192.f) - mean * mean;
    const float rstd = rsqrtf(var + 1e-5f);
    const int c0 = l4 * 48;
    #pragma unroll
    for (int i = 0; i < 12; ++i) {
      ushort4 o;
      o.x = f2bf((rv[i*4+0] - mean) * rstd * g2[c0+i*4+0] + b2[c0+i*4+0]);
      o.y = f2bf((rv[i*4+1] - mean) * rstd * g2[c0+i*4+1] + b2[c0+i*4+1]);
      o.z = f2bf((rv[i*4+2] - mean) * rstd * g2[c0+i*4+2] + b2[c0+i*4+2]);
      o.w = f2bf((rv[i*4+3] - mean) * rstd * g2[c0+i*4+3] + b2[c0+i*4+3]);
      *(ushort4*)&shbuf[t * 200 + c0 + i*4] = o;
    }
  }
  __syncthreads();                 // xn ready

  // A-fragments are chunk-invariant: hoist once (24 VGPRs); xn dead after.
  short8 a_all[6];
  #pragma unroll
  for (int s = 0; s < 6; ++s)
    a_all[s] = *(const short8*)&shbuf[(16 * w + m) * 200 + 32 * s + 8 * q];
  __syncthreads();                 // all waves done reading xn

  // commit chunk 0 w1 into wbuf[0] (overlays xn)
  #pragma unroll
  for (int it = 0; it < 3; ++it)
    *(short8*)&shbuf[(it * 256 + tid) * 8] = pf1[it];
  // stage chunk 1 w1
  {
    const u16* p1 = wsm1 + 6144;
    #pragma unroll
    for (int it = 0; it < 3; ++it)
      pf1[it] = *(const short8*)(p1 + (it * 256 + tid) * 8);
  }
  __syncthreads();                 // wbuf[0] ready

  floatx4 c2acc[12];
  #pragma unroll
  for (int ct = 0; ct < 12; ++ct) c2acc[ct] = (floatx4){0.f, 0.f, 0.f, 0.f};

  #pragma unroll 1
  for (int ch = 0; ch < 24; ++ch) {
    const int buf = ch & 1;

    // w2 B-frags for this chunk: 12 independent global loads (L2-resident),
    // issued now, consumed after GELU -> latency hidden by GEMM1+GELU.
    short8 w2r[12];
    {
      const u16* w2p = wsm2 + (size_t)ch * 6144 + lane * 8;
      #pragma unroll
      for (int ct = 0; ct < 12; ++ct)
        w2r[ct] = *(const short8*)(w2p + ct * 512);
    }

    // GEMM1: H tile 16x32, K=192 (6 ksteps) from LDS w1
    const u16* w1p = shbuf + buf * 6144 + lane * 8;
    floatx4 h0 = (floatx4){0.f, 0.f, 0.f, 0.f};
    floatx4 h1 = (floatx4){0.f, 0.f, 0.f, 0.f};
    #pragma unroll
    for (int s = 0; s < 6; ++s) {
      short8 b0 = *(const short8*)(w1p + s * 512);
      short8 b1 = *(const short8*)(w1p + 3072 + s * 512);
      h0 = __builtin_amdgcn_mfma_f32_16x16x32_bf16(a_all[s], b0, h0, 0, 0, 0);
      h1 = __builtin_amdgcn_mfma_f32_16x16x32_bf16(a_all[s], b1, h1, 0, 0, 0);
    }

    // bias + exact GELU, wave-private LDS transpose (no barrier needed)
    const int c0 = ch * 32;
    {
      const float bb0 = bm1[c0 + m];
      const float bb1 = bm1[c0 + 16 + m];
      #pragma unroll
      for (int r = 0; r < 4; ++r) {
        float v0 = h0[r] + bb0;
        float v1 = h1[r] + bb1;
        float g0 = 0.5f * v0 * (1.f + erff(v0 * 0.70710678118654752f));
        float g1 = 0.5f * v1 * (1.f + erff(v1 * 0.70710678118654752f));
        gs[w][q * 4 + r][m] = f2bf(g0);
        gs[w][q * 4 + r][16 + m] = f2bf(g1);
      }
    }

    // GEMM2: C2[16x192] += G[16x32] @ w2chunk, K=32; B from registers
    {
      short8 ap = *(const short8*)&gs[w][m][8 * q];
      #pragma unroll
      for (int ct = 0; ct < 12; ++ct)
        c2acc[ct] = __builtin_amdgcn_mfma_f32_16x16x32_bf16(ap, w2r[ct], c2acc[ct], 0, 0, 0);
    }

    if (ch + 1 < 24) {
      // commit next chunk's w1 (other buffer), then stage chunk after next
      #pragma unroll
      for (int it = 0; it < 3; ++it)
        *(short8*)&shbuf[(buf ^ 1) * 6144 + (it * 256 + tid) * 8] = pf1[it];
      if (ch + 2 < 24) {
        const u16* p1 = wsm1 + (size_t)(ch + 2) * 6144;
        #pragma unroll
        for (int it = 0; it < 3; ++it)
          pf1[it] = *(const short8*)(p1 + (it * 256 + tid) * 8);
      }
      __syncthreads();             // wbuf[buf^1] staged for next chunk
    }
  }

  // ---- epilogue: out = x1 + C2 + bias (C/D layout: row=q*4+r, col=ct*16+m) ----
  #pragma unroll
  for (int ct = 0; ct < 12; ++ct) {
    const int c = ct * 16 + m;
    const float bb = bm2[c];
    #pragma unroll
    for (int r = 0; r < 4; ++r) {
      const size_t idx = (tok0 + 16 * w + q * 4 + r) * 192 + c;
      io[idx] = c2acc[ct][r] + bb + io[idx];
    }
  }
}

extern "C" void kernel_launch(void* const* d_in, const int* in_sizes, int n_in,
                              void* d_out, int out_size, void* d_ws, size_t ws_size,
                              hipStream_t stream) {
  (void)in_sizes; (void)n_in; (void)out_size; (void)ws_size;
  const float* x    = (const float*)d_in[0];
  const float* n1g  = (const float*)d_in[1];
  const float* n1b  = (const float*)d_in[2];
  const float* qkvw = (const float*)d_in[3];
  const float* rpb  = (const float*)d_in[4];
  const float* pw   = (const float*)d_in[5];
  const float* pb   = (const float*)d_in[6];
  const float* n2g  = (const float*)d_in[7];
  const float* n2b  = (const float*)d_in[8];
  const float* w1   = (const float*)d_in[9];
  const float* bm1  = (const float*)d_in[10];
  const float* w2   = (const float*)d_in[11];
  const float* bm2  = (const float*)d_in[12];
  float* out = (float*)d_out;

  float* wsb  = (float*)((char*)d_ws + WSB_OFF);
  u16*   wsq  = (u16*)((char*)d_ws + WSQ_OFF);
  u16*   wsp  = (u16*)((char*)d_ws + WSP_OFF);
  u16*   wsm1 = (u16*)((char*)d_ws + WSM1_OFF);
  u16*   wsm2 = (u16*)((char*)d_ws + WSM2_OFF);

  hipLaunchKernelGGL(k_prep, dim3(192), dim3(256), 0, stream,
                     qkvw, pw, rpb, w1, w2, wsb, wsq, wsp, wsm1, wsm2);
  hipLaunchKernelGGL(k_attn, dim3(2048), dim3(256), 0, stream,
                     x, n1g, n1b, pb, wsb, wsq, wsp, out);
  hipLaunchKernelGGL(k_mlp, dim3(2048), dim3(256), 0, stream,
                     n2g, n2b, wsm1, bm1, wsm2, bm2, out);
}